// Round 4
// baseline (302.182 us; speedup 1.0000x reference)
//
#include <hip/hip_runtime.h>
#include <math.h>

// B=8, N=2048, Fin=Fout=512, fp32 in/out. bf16 MFMA internally.
// out[n,o] = sum_m exp(adj[n,m]) * (sup[m,o] / D[m]),  D[m] = sum_n exp(adj[n,m])
#define BB 8
#define NN 2048
#define FF 512

typedef __attribute__((ext_vector_type(8))) short short8;
typedef __attribute__((ext_vector_type(4))) float floatx4;
typedef __attribute__((ext_vector_type(4))) unsigned short ushort4v;

__device__ __forceinline__ unsigned short f2bf(float f) {
    union { float f; unsigned u; } v; v.f = f;
    unsigned r = v.u + 0x7FFFu + ((v.u >> 16) & 1u);
    return (unsigned short)(r >> 16);
}

// ---------------------------------------------------------------------------
// Transposed-output BT-GEMM, bf16 MFMA:
//   O[jn, im] = sum_k B[jn*b_ld + k] * A[im*a_ld + k]      (O rows = B-rows,
//   O cols = A-rows; ldc = A-row count M). A-row dim is the MFMA row dim
//   (quad*4+r, contiguous per lane) -> vector stores along O's fast axis.
// modes: 0 = fp32 out + bias[col] (float4 stores)
//        1 = bf16 out (short4 stores)
//        2 = bf16 exp(out) + Dsum[col] += colsum (short4 stores)
// 128x128 tile, BK=32, 256 thr = 4 waves (2x2), 4x4 16x16x32 frags/wave.
// LDS K-chunk XOR swizzle kills the 8-way ds_read_b128 bank conflict.
// ---------------------------------------------------------------------------
__global__ __launch_bounds__(256) void gemm_mfma_bt(
    const unsigned short* __restrict__ A, const unsigned short* __restrict__ B,
    void* __restrict__ Ov, const float* __restrict__ bias, float* __restrict__ Dsum,
    int M, int Nc, int K, int a_ld, int b_ld, int ldc,
    long a_batch, long b_batch, long c_batch, int mode)
{
    __shared__ __align__(16) unsigned short Alds[128 * 32];
    __shared__ __align__(16) unsigned short Blds[128 * 32];

    const int tid  = threadIdx.x;
    const int wave = tid >> 6;
    const int lane = tid & 63;
    const int bz   = blockIdx.z;

    const unsigned short* Ab = A + (long)bz * a_batch;
    const unsigned short* Bb = B + (long)bz * b_batch;

    const int m0 = blockIdx.y * 128;   // A-row tile (O columns)
    const int n0 = blockIdx.x * 128;   // B-row tile (O rows)

    const int wm   = (wave >> 1) * 64;
    const int wn   = (wave & 1) * 64;
    const int fl   = lane & 15;
    const int quad = lane >> 4;

    // staging: chunk c -> row c>>2; source kq XOR-swizzled so LDS slot (row,kq)
    // holds global chunk (row, kq^((row>>1)&3)). Same 64B row -> coalescing kept.
    const int src_kq0 = ((lane & 3) ^ ((lane >> 3) & 3)) * 8;
    // reader: chunk (row, quad) lives at slot kq = quad ^ ((row>>1)&3);
    // row = wm/wn + i*16 + fl and wm,i*16 are multiples of 16 -> lane-constant:
    const int jsw = (quad ^ ((fl >> 1) & 3)) * 8;

    floatx4 acc[4][4] = {};

    for (int k0 = 0; k0 < K; k0 += 32) {
        #pragma unroll
        for (int issue = 0; issue < 2; ++issue) {
            const int cbase = issue * 256 + wave * 64;
            const int c = cbase + lane;
            const int row = c >> 2;
            const int kq = ((c & 3) ^ ((c >> 3) & 3)) * 8;  // == src_kq0 pattern
            (void)src_kq0;
            const unsigned short* gA = Ab + (long)(m0 + row) * a_ld + k0 + kq;
            __builtin_amdgcn_global_load_lds(
                (const __attribute__((address_space(1))) void*)gA,
                (__attribute__((address_space(3))) void*)&Alds[cbase * 8], 16, 0, 0);
            const unsigned short* gB = Bb + (long)(n0 + row) * b_ld + k0 + kq;
            __builtin_amdgcn_global_load_lds(
                (const __attribute__((address_space(1))) void*)gB,
                (__attribute__((address_space(3))) void*)&Blds[cbase * 8], 16, 0, 0);
        }
        __syncthreads();

        short8 af[4], bf[4];
        #pragma unroll
        for (int i = 0; i < 4; ++i)
            af[i] = *(const short8*)&Alds[(wm + i * 16 + fl) * 32 + jsw];
        #pragma unroll
        for (int j = 0; j < 4; ++j)
            bf[j] = *(const short8*)&Blds[(wn + j * 16 + fl) * 32 + jsw];

        #pragma unroll
        for (int i = 0; i < 4; ++i)
            #pragma unroll
            for (int j = 0; j < 4; ++j)
                acc[i][j] = __builtin_amdgcn_mfma_f32_16x16x32_bf16(af[i], bf[j], acc[i][j], 0, 0, 0);
        __syncthreads();
    }

    // Epilogue. MFMA C/D layout: col(j-dim) = lane&15, row(i-dim) = quad*4+reg.
    // Here i-dim = A-rows = O columns (fast axis) -> per-lane r=0..3 contiguous.
    if (mode == 0) {
        float* Ob = (float*)Ov + (long)bz * c_batch;
        #pragma unroll
        for (int j = 0; j < 4; ++j) {
            const int ng = n0 + wn + j * 16 + fl;       // O row
            #pragma unroll
            for (int i = 0; i < 4; ++i) {
                const int mg = m0 + wm + i * 16 + quad * 4;  // O col base
                float4 b4 = *(const float4*)&bias[mg];
                float4 v;
                v.x = acc[i][j][0] + b4.x; v.y = acc[i][j][1] + b4.y;
                v.z = acc[i][j][2] + b4.z; v.w = acc[i][j][3] + b4.w;
                *(float4*)&Ob[(long)ng * ldc + mg] = v;
            }
        }
    } else if (mode == 1) {
        unsigned short* Ob = (unsigned short*)Ov + (long)bz * c_batch;
        #pragma unroll
        for (int j = 0; j < 4; ++j) {
            const int ng = n0 + wn + j * 16 + fl;
            #pragma unroll
            for (int i = 0; i < 4; ++i) {
                const int mg = m0 + wm + i * 16 + quad * 4;
                ushort4v o;
                o[0] = f2bf(acc[i][j][0]); o[1] = f2bf(acc[i][j][1]);
                o[2] = f2bf(acc[i][j][2]); o[3] = f2bf(acc[i][j][3]);
                *(ushort4v*)&Ob[(long)ng * ldc + mg] = o;
            }
        }
    } else {
        // mode 2: E = exp(acc), bf16 stores; Dsum[col] += sum over O-rows.
        unsigned short* Ob = (unsigned short*)Ov + (long)bz * c_batch;
        float* Db = Dsum + (long)bz * NN;
        #pragma unroll
        for (int i = 0; i < 4; ++i)
            #pragma unroll
            for (int j = 0; j < 4; ++j)
                #pragma unroll
                for (int r = 0; r < 4; ++r)
                    acc[i][j][r] = __expf(acc[i][j][r]);
        #pragma unroll
        for (int j = 0; j < 4; ++j) {
            const int ng = n0 + wn + j * 16 + fl;
            #pragma unroll
            for (int i = 0; i < 4; ++i) {
                const int mg = m0 + wm + i * 16 + quad * 4;
                ushort4v o;
                o[0] = f2bf(acc[i][j][0]); o[1] = f2bf(acc[i][j][1]);
                o[2] = f2bf(acc[i][j][2]); o[3] = f2bf(acc[i][j][3]);
                *(ushort4v*)&Ob[(long)ng * ldc + mg] = o;
            }
        }
        // column sums: reduce over j (in-lane) then over fl (butterfly).
        #pragma unroll
        for (int i = 0; i < 4; ++i) {
            #pragma unroll
            for (int r = 0; r < 4; ++r) {
                float rs = acc[i][0][r] + acc[i][1][r] + acc[i][2][r] + acc[i][3][r];
                rs += __shfl_xor(rs, 1);
                rs += __shfl_xor(rs, 2);
                rs += __shfl_xor(rs, 4);
                rs += __shfl_xor(rs, 8);
                if (fl == 0)
                    atomicAdd(&Db[m0 + wm + i * 16 + quad * 4 + r], rs);
            }
        }
    }
}

// fused fp32->bf16 convert for x, w_one, w_two (8 elems/thread, region split)
__global__ __launch_bounds__(256) void convert_all(
    const float* __restrict__ x, const float* __restrict__ w1, const float* __restrict__ w2,
    unsigned short* __restrict__ xb, unsigned short* __restrict__ w1b, unsigned short* __restrict__ w2b)
{
    const long NX = (long)BB * NN * FF / 8;
    const long NW = (long)FF * FF / 8;
    long t = (long)blockIdx.x * 256 + threadIdx.x;
    const float* in; unsigned short* out;
    if (t < NX) { in = x; out = xb; }
    else if (t < NX + NW) { in = w1; out = w1b; t -= NX; }
    else if (t < NX + 2 * NW) { in = w2; out = w2b; t -= NX + NW; }
    else return;
    const long i = t * 8;
    float4 a = *(const float4*)(in + i);
    float4 b = *(const float4*)(in + i + 4);
    short8 o;
    o[0] = (short)f2bf(a.x); o[1] = (short)f2bf(a.y);
    o[2] = (short)f2bf(a.z); o[3] = (short)f2bf(a.w);
    o[4] = (short)f2bf(b.x); o[5] = (short)f2bf(b.y);
    o[6] = (short)f2bf(b.z); o[7] = (short)f2bf(b.w);
    *(short8*)(out + i) = o;
}

// out[o,f] = bf16(in[f,o]) for dim x dim fp32 (dim % 32 == 0)
__global__ __launch_bounds__(256) void transpose_convert(
    const float* __restrict__ in, unsigned short* __restrict__ out, int dim)
{
    __shared__ float t[32][33];
    const int tx = threadIdx.x & 31, ty = threadIdx.x >> 5;
    const int x0 = blockIdx.x * 32, y0 = blockIdx.y * 32;
    #pragma unroll
    for (int k = 0; k < 32; k += 8)
        t[ty + k][tx] = in[(long)(y0 + ty + k) * dim + x0 + tx];
    __syncthreads();
    #pragma unroll
    for (int k = 0; k < 32; k += 8)
        out[(long)(x0 + ty + k) * dim + y0 + tx] = f2bf(t[tx][ty + k]);
}

__global__ __launch_bounds__(256) void zero_f32(float* __restrict__ p, long n)
{
    long i = (long)blockIdx.x * 256 + threadIdx.x;
    if (i < n) p[i] = 0.0f;
}

// supT[o,m] = bf16( sup[m,o] / D[m] ); sup[m,o] = Call[m*1536 + 1024 + o] (bf16).
__global__ __launch_bounds__(256) void scale_transpose(
    const unsigned short* __restrict__ Call, const float* __restrict__ D,
    unsigned short* __restrict__ supT, int batch0)
{
    __shared__ float t[32][33];
    __shared__ float rD[32];
    const int tx = threadIdx.x & 31, ty = threadIdx.x >> 5;
    const int mt = blockIdx.x * 32, ot = blockIdx.y * 32;
    const int b = batch0 + blockIdx.z;
    const unsigned short* Cb = Call + (long)b * NN * 1536;
    unsigned short* Tb = supT + (long)b * NN * FF;
    if (threadIdx.x < 32) rD[threadIdx.x] = 1.0f / D[(long)b * NN + mt + threadIdx.x];
    __syncthreads();
    #pragma unroll
    for (int k = 0; k < 32; k += 8) {
        unsigned short u = Cb[(long)(mt + ty + k) * 1536 + 1024 + ot + tx];
        union { unsigned uu; float f; } cv; cv.uu = ((unsigned)u) << 16;
        t[ty + k][tx] = cv.f;
    }
    __syncthreads();
    #pragma unroll
    for (int k = 0; k < 32; k += 8)
        Tb[(long)(ot + ty + k) * NN + mt + tx] = f2bf(t[tx][ty + k] * rD[tx]);
}

extern "C" void kernel_launch(void* const* d_in, const int* in_sizes, int n_in,
                              void* d_out, int out_size, void* d_ws, size_t ws_size,
                              hipStream_t stream)
{
    const float* x      = (const float*)d_in[0];
    const float* weight = (const float*)d_in[1];
    const float* bias   = (const float*)d_in[2];
    const float* w_one  = (const float*)d_in[3];
    const float* w_two  = (const float*)d_in[4];
    float* out = (float*)d_out;

    const long NF  = (long)NN * FF;      // 1,048,576
    const long NN2 = (long)NN * NN;      // 4,194,304
    const long CROW = 1536;              // C_all row stride (p1|p2|sup)

    // workspace carve
    char* p = (char*)d_ws;
    unsigned short* xb    = (unsigned short*)p; p += (size_t)BB * NF * 2;          // 16 MB
    unsigned short* Wall  = (unsigned short*)p; p += (size_t)CROW * FF * 2;        // 1.5 MB
    unsigned short* Call  = (unsigned short*)p; p += (size_t)BB * NN * CROW * 2;   // 48 MB
    unsigned short* supT  = (unsigned short*)p; p += (size_t)BB * NF * 2;          // 16 MB
    float*          Dsum  = (float*)p;          p += (size_t)BB * NN * 4;          // 64 KB
    unsigned short* E     = (unsigned short*)p;                                    // 64 MB (full) or 8 MB (batch)
    unsigned short* w1b = Wall;
    unsigned short* w2b = Wall + (size_t)FF * FF;
    unsigned short* wTb = Wall + (size_t)2 * FF * FF;

    const size_t fixed = (size_t)(p - (char*)d_ws);
    const bool full = ws_size >= fixed + (size_t)BB * NN2 * 2;

    dim3 blk(256);

    // 1) converts
    convert_all<<<dim3(4352), blk, 0, stream>>>(x, w_one, w_two, xb, w1b, w2b);
    transpose_convert<<<dim3(FF / 32, FF / 32), blk, 0, stream>>>(weight, wTb, FF);
    zero_f32<<<dim3((BB * NN) / 256), blk, 0, stream>>>(Dsum, BB * NN);

    // 2) Call[n, e] = x[n,:]·Wall[e,:]  (O rows = n from B=xb, cols = e from A=Wall)
    gemm_mfma_bt<<<dim3(NN / 128, CROW / 128, BB), blk, 0, stream>>>(
        Wall, xb, Call, nullptr, nullptr, (int)CROW, NN, FF,
        FF, FF, (int)CROW, 0, NF, NN * CROW, 1);

    if (full) {
        // 3) E[n,m] = exp(p1[n,:]·p2[m,:]); Dsum[b,m] += colsums.
        //    A = p2 (cols m), B = p1 (rows n).
        gemm_mfma_bt<<<dim3(NN / 128, NN / 128, BB), blk, 0, stream>>>(
            Call + FF, Call, E, nullptr, Dsum, NN, NN, FF,
            (int)CROW, (int)CROW, NN, NN * CROW, NN * CROW, NN2, 2);
        // 4) supT[o,m] = sup[m,o]/D[m]
        scale_transpose<<<dim3(NN / 32, FF / 32, BB), blk, 0, stream>>>(Call, Dsum, supT, 0);
        // 5) out[n,o] = E[n,:]·supT[o,:] + bias[o]  (A = supT cols o, B = E rows n)
        gemm_mfma_bt<<<dim3(NN / 128, FF / 128, BB), blk, 0, stream>>>(
            supT, E, out, bias, nullptr, FF, NN, NN,
            NN, NN, FF, NF, NN2, NF, 0);
    } else {
        for (int b = 0; b < BB; ++b) {
            const unsigned short* Cb = Call + (size_t)b * NN * CROW;
            gemm_mfma_bt<<<dim3(NN / 128, NN / 128, 1), blk, 0, stream>>>(
                Cb + FF, Cb, E, nullptr, Dsum + (size_t)b * NN, NN, NN, FF,
                (int)CROW, (int)CROW, NN, 0, 0, 0, 2);
            scale_transpose<<<dim3(NN / 32, FF / 32, 1), blk, 0, stream>>>(Call, Dsum, supT, b);
            gemm_mfma_bt<<<dim3(NN / 128, FF / 128, 1), blk, 0, stream>>>(
                supT + (size_t)b * NF, E, out + (size_t)b * NF, bias, nullptr, FF, NN, NN,
                NN, NN, FF, 0, 0, 0, 0);
        }
    }
}

// Round 5
// 240.672 us; speedup vs baseline: 1.2556x; 1.2556x over previous
//
#include <hip/hip_runtime.h>
#include <math.h>

// B=8, N=2048, Fin=Fout=512, fp32 in/out. bf16 MFMA internally.
// out[n,o] = sum_m exp(adj[n,m]) * (sup[m,o] / D[m]),  D[m] = sum_n exp(adj[n,m])
#define BB 8
#define NN 2048
#define FF 512

typedef __attribute__((ext_vector_type(8))) short short8;
typedef __attribute__((ext_vector_type(4))) float floatx4;

__device__ __forceinline__ unsigned short f2bf(float f) {
    union { float f; unsigned u; } v; v.f = f;
    unsigned r = v.u + 0x7FFFu + ((v.u >> 16) & 1u);
    return (unsigned short)(r >> 16);
}

// ---------------------------------------------------------------------------
// BT-GEMM, bf16 MFMA: C[i,j] = sum_k A[i*a_ld+k] * B[j*b_ld+k]
// C row i = A row (MFMA i-dim: quad*4+reg), C col j = B row (MFMA j-dim: fl)
// -> stores are inter-lane contiguous along j (16 lanes x consecutive cols).
// modes: 0 = fp32 out + bias[j]; 1 = bf16 out; 2 = bf16 exp(out) + Dsum[j] colsum
// 128x128 tile, BK=64 (32 KB LDS), 256 thr = 4 waves (2x2), 4x4 16x16x32 frags.
// LDS chunk XOR swizzle: slot kc^(row&7) -> readers spread 8 chunk-cols, 2-way
// (free, m136); staging source permutes within each 128B row (coalescing kept).
// ---------------------------------------------------------------------------
__global__ __launch_bounds__(256) void gemm_mfma_bt(
    const unsigned short* __restrict__ A, const unsigned short* __restrict__ B,
    void* __restrict__ Cv, const float* __restrict__ bias, float* __restrict__ Dsum,
    int M, int Nc, int K, int a_ld, int b_ld, int ldc,
    long a_batch, long b_batch, long c_batch, int mode)
{
    __shared__ __align__(16) unsigned short Alds[128 * 64];
    __shared__ __align__(16) unsigned short Blds[128 * 64];

    const int tid  = threadIdx.x;
    const int wave = tid >> 6;
    const int lane = tid & 63;
    const int bz   = blockIdx.z;

    const unsigned short* Ab = A + (long)bz * a_batch;
    const unsigned short* Bb = B + (long)bz * b_batch;

    const int m0 = blockIdx.y * 128;   // A-row tile (C rows)
    const int n0 = blockIdx.x * 128;   // B-row tile (C cols)

    const int wm   = (wave >> 1) * 64;
    const int wn   = (wave & 1) * 64;
    const int fl   = lane & 15;
    const int quad = lane >> 4;

    floatx4 acc[4][4] = {};

    for (int k0 = 0; k0 < K; k0 += 64) {
        // stage 128 rows x 64 k bf16 = 16 KB each = 1024 x 16B chunks, 4 issues.
        // chunk c: row = c>>3, LDS slot = c&7, global source kq = (c&7)^((c>>3)&7).
        #pragma unroll
        for (int issue = 0; issue < 4; ++issue) {
            const int cbase = issue * 256 + wave * 64;
            const int c = cbase + lane;
            const int row = c >> 3;
            const int kq = ((c & 7) ^ ((c >> 3) & 7)) * 8;
            const unsigned short* gA = Ab + (long)(m0 + row) * a_ld + k0 + kq;
            __builtin_amdgcn_global_load_lds(
                (const __attribute__((address_space(1))) void*)gA,
                (__attribute__((address_space(3))) void*)&Alds[cbase * 8], 16, 0, 0);
            const unsigned short* gB = Bb + (long)(n0 + row) * b_ld + k0 + kq;
            __builtin_amdgcn_global_load_lds(
                (const __attribute__((address_space(1))) void*)gB,
                (__attribute__((address_space(3))) void*)&Blds[cbase * 8], 16, 0, 0);
        }
        __syncthreads();

        // two MFMA k-steps per staged tile; chunk (row, kc) at slot kc^(row&7),
        // row&7 == fl&7 here (wm, i*16 are multiples of 16).
        #pragma unroll
        for (int s = 0; s < 2; ++s) {
            short8 af[4], bf[4];
            #pragma unroll
            for (int i = 0; i < 4; ++i) {
                const int slot = ((s * 4 + quad) ^ (fl & 7)) * 8;
                af[i] = *(const short8*)&Alds[(wm + i * 16 + fl) * 64 + slot];
            }
            #pragma unroll
            for (int j = 0; j < 4; ++j) {
                const int slot = ((s * 4 + quad) ^ (fl & 7)) * 8;
                bf[j] = *(const short8*)&Blds[(wn + j * 16 + fl) * 64 + slot];
            }
            #pragma unroll
            for (int i = 0; i < 4; ++i)
                #pragma unroll
                for (int j = 0; j < 4; ++j)
                    acc[i][j] = __builtin_amdgcn_mfma_f32_16x16x32_bf16(af[i], bf[j], acc[i][j], 0, 0, 0);
        }
        __syncthreads();
    }

    // Epilogue (round-3 orientation): col(j) = fl across lanes -> 32B contiguous
    // per quad per store instruction; L2 merges adjacent-j halves of each line.
    if (mode == 0) {
        float* Cb = (float*)Cv + (long)bz * c_batch;
        #pragma unroll
        for (int j = 0; j < 4; ++j) {
            const int ng = n0 + wn + j * 16 + fl;
            const float badd = bias ? bias[ng] : 0.0f;
            #pragma unroll
            for (int i = 0; i < 4; ++i) {
                const int mg = m0 + wm + i * 16 + quad * 4;
                #pragma unroll
                for (int r = 0; r < 4; ++r)
                    Cb[(long)(mg + r) * ldc + ng] = acc[i][j][r] + badd;
            }
        }
    } else if (mode == 1) {
        unsigned short* Cb = (unsigned short*)Cv + (long)bz * c_batch;
        #pragma unroll
        for (int j = 0; j < 4; ++j) {
            const int ng = n0 + wn + j * 16 + fl;
            #pragma unroll
            for (int i = 0; i < 4; ++i) {
                const int mg = m0 + wm + i * 16 + quad * 4;
                #pragma unroll
                for (int r = 0; r < 4; ++r)
                    Cb[(long)(mg + r) * ldc + ng] = f2bf(acc[i][j][r]);
            }
        }
    } else {
        // mode 2: E = exp(acc) bf16; Dsum[col] += column partial sums.
        unsigned short* Cb = (unsigned short*)Cv + (long)bz * c_batch;
        float* Db = Dsum + (long)bz * NN;
        #pragma unroll
        for (int j = 0; j < 4; ++j) {
            const int ng = n0 + wn + j * 16 + fl;
            float csum = 0.f;
            #pragma unroll
            for (int i = 0; i < 4; ++i) {
                const int mg = m0 + wm + i * 16 + quad * 4;
                #pragma unroll
                for (int r = 0; r < 4; ++r) {
                    const float e = __expf(acc[i][j][r]);
                    csum += e;
                    Cb[(long)(mg + r) * ldc + ng] = f2bf(e);
                }
            }
            csum += __shfl_xor(csum, 16);
            csum += __shfl_xor(csum, 32);
            if (quad == 0) atomicAdd(&Db[ng], csum);
        }
    }
}

// fused fp32->bf16 convert for x, w_one, w_two (8 elems/thread, region split)
__global__ __launch_bounds__(256) void convert_all(
    const float* __restrict__ x, const float* __restrict__ w1, const float* __restrict__ w2,
    unsigned short* __restrict__ xb, unsigned short* __restrict__ w1b, unsigned short* __restrict__ w2b)
{
    const long NX = (long)BB * NN * FF / 8;
    const long NW = (long)FF * FF / 8;
    long t = (long)blockIdx.x * 256 + threadIdx.x;
    const float* in; unsigned short* out;
    if (t < NX) { in = x; out = xb; }
    else if (t < NX + NW) { in = w1; out = w1b; t -= NX; }
    else if (t < NX + 2 * NW) { in = w2; out = w2b; t -= NX + NW; }
    else return;
    const long i = t * 8;
    float4 a = *(const float4*)(in + i);
    float4 b = *(const float4*)(in + i + 4);
    short8 o;
    o[0] = (short)f2bf(a.x); o[1] = (short)f2bf(a.y);
    o[2] = (short)f2bf(a.z); o[3] = (short)f2bf(a.w);
    o[4] = (short)f2bf(b.x); o[5] = (short)f2bf(b.y);
    o[6] = (short)f2bf(b.z); o[7] = (short)f2bf(b.w);
    *(short8*)(out + i) = o;
}

// out[o,f] = bf16(in[f,o]) for dim x dim fp32 (dim % 32 == 0)
__global__ __launch_bounds__(256) void transpose_convert(
    const float* __restrict__ in, unsigned short* __restrict__ out, int dim)
{
    __shared__ float t[32][33];
    const int tx = threadIdx.x & 31, ty = threadIdx.x >> 5;
    const int x0 = blockIdx.x * 32, y0 = blockIdx.y * 32;
    #pragma unroll
    for (int k = 0; k < 32; k += 8)
        t[ty + k][tx] = in[(long)(y0 + ty + k) * dim + x0 + tx];
    __syncthreads();
    #pragma unroll
    for (int k = 0; k < 32; k += 8)
        out[(long)(x0 + ty + k) * dim + y0 + tx] = f2bf(t[tx][ty + k]);
}

__global__ __launch_bounds__(256) void zero_f32(float* __restrict__ p, long n)
{
    long i = (long)blockIdx.x * 256 + threadIdx.x;
    if (i < n) p[i] = 0.0f;
}

// supT[o,m] = bf16( sup[m,o] / D[m] ); sup[m,o] = Call[m*1536 + 1024 + o] (bf16).
__global__ __launch_bounds__(256) void scale_transpose(
    const unsigned short* __restrict__ Call, const float* __restrict__ D,
    unsigned short* __restrict__ supT, int batch0)
{
    __shared__ float t[32][33];
    __shared__ float rD[32];
    const int tx = threadIdx.x & 31, ty = threadIdx.x >> 5;
    const int mt = blockIdx.x * 32, ot = blockIdx.y * 32;
    const int b = batch0 + blockIdx.z;
    const unsigned short* Cb = Call + (long)b * NN * 1536;
    unsigned short* Tb = supT + (long)b * NN * FF;
    if (threadIdx.x < 32) rD[threadIdx.x] = 1.0f / D[(long)b * NN + mt + threadIdx.x];
    __syncthreads();
    #pragma unroll
    for (int k = 0; k < 32; k += 8) {
        unsigned short u = Cb[(long)(mt + ty + k) * 1536 + 1024 + ot + tx];
        union { unsigned uu; float f; } cv; cv.uu = ((unsigned)u) << 16;
        t[ty + k][tx] = cv.f;
    }
    __syncthreads();
    #pragma unroll
    for (int k = 0; k < 32; k += 8)
        Tb[(long)(ot + ty + k) * NN + mt + tx] = f2bf(t[tx][ty + k] * rD[tx]);
}

extern "C" void kernel_launch(void* const* d_in, const int* in_sizes, int n_in,
                              void* d_out, int out_size, void* d_ws, size_t ws_size,
                              hipStream_t stream)
{
    const float* x      = (const float*)d_in[0];
    const float* weight = (const float*)d_in[1];
    const float* bias   = (const float*)d_in[2];
    const float* w_one  = (const float*)d_in[3];
    const float* w_two  = (const float*)d_in[4];
    float* out = (float*)d_out;

    const long NF  = (long)NN * FF;      // 1,048,576
    const long NN2 = (long)NN * NN;      // 4,194,304
    const long CROW = 1536;              // C_all row stride (p1|p2|sup)

    // workspace carve
    char* p = (char*)d_ws;
    unsigned short* xb    = (unsigned short*)p; p += (size_t)BB * NF * 2;          // 16 MB
    unsigned short* Wall  = (unsigned short*)p; p += (size_t)CROW * FF * 2;        // 1.5 MB
    unsigned short* Call  = (unsigned short*)p; p += (size_t)BB * NN * CROW * 2;   // 48 MB
    unsigned short* supT  = (unsigned short*)p; p += (size_t)BB * NF * 2;          // 16 MB
    float*          Dsum  = (float*)p;          p += (size_t)BB * NN * 4;          // 64 KB
    unsigned short* E     = (unsigned short*)p;                                    // 64 MB (full) or 8 MB (batch)
    unsigned short* w1b = Wall;
    unsigned short* w2b = Wall + (size_t)FF * FF;
    unsigned short* wTb = Wall + (size_t)2 * FF * FF;

    const size_t fixed = (size_t)(p - (char*)d_ws);
    const bool full = ws_size >= fixed + (size_t)BB * NN2 * 2;

    dim3 blk(256);

    // 1) converts
    convert_all<<<dim3(4352), blk, 0, stream>>>(x, w_one, w_two, xb, w1b, w2b);
    transpose_convert<<<dim3(FF / 32, FF / 32), blk, 0, stream>>>(weight, wTb, FF);
    zero_f32<<<dim3((BB * NN) / 256), blk, 0, stream>>>(Dsum, BB * NN);

    // 2) Call[n, e] = x[n,:]·Wall[e,:]   (rows n = A = xb, cols e = B = Wall)
    gemm_mfma_bt<<<dim3(CROW / 128, NN / 128, BB), blk, 0, stream>>>(
        xb, Wall, Call, nullptr, nullptr, NN, (int)CROW, FF,
        FF, FF, (int)CROW, NF, 0, NN * CROW, 1);

    if (full) {
        // 3) E[n,m] = exp(p1[n,:]·p2[m,:]); Dsum[b,m] += colsums.
        gemm_mfma_bt<<<dim3(NN / 128, NN / 128, BB), blk, 0, stream>>>(
            Call, Call + FF, E, nullptr, Dsum, NN, NN, FF,
            (int)CROW, (int)CROW, NN, NN * CROW, NN * CROW, NN2, 2);
        // 4) supT[o,m] = sup[m,o]/D[m]
        scale_transpose<<<dim3(NN / 32, FF / 32, BB), blk, 0, stream>>>(Call, Dsum, supT, 0);
        // 5) out[n,o] = E[n,:]·supT[o,:] + bias[o]
        gemm_mfma_bt<<<dim3(FF / 128, NN / 128, BB), blk, 0, stream>>>(
            E, supT, out, bias, nullptr, NN, FF, NN,
            NN, NN, FF, NN2, NF, NF, 0);
    } else {
        for (int b = 0; b < BB; ++b) {
            const unsigned short* Cb = Call + (size_t)b * NN * CROW;
            gemm_mfma_bt<<<dim3(NN / 128, NN / 128, 1), blk, 0, stream>>>(
                Cb, Cb + FF, E, nullptr, Dsum + (size_t)b * NN, NN, NN, FF,
                (int)CROW, (int)CROW, NN, 0, 0, 0, 2);
            scale_transpose<<<dim3(NN / 32, FF / 32, 1), blk, 0, stream>>>(Call, Dsum, supT, b);
            gemm_mfma_bt<<<dim3(FF / 128, NN / 128, 1), blk, 0, stream>>>(
                E, supT + (size_t)b * NF, out + (size_t)b * NF, bias, nullptr, NN, FF, NN,
                NN, NN, FF, 0, 0, 0, 0);
        }
    }
}

// Round 6
// 240.564 us; speedup vs baseline: 1.2561x; 1.0004x over previous
//
#include <hip/hip_runtime.h>
#include <math.h>

// B=8, N=2048, Fin=Fout=512, fp32 in/out. bf16 MFMA internally.
// out[n,o] = sum_m exp(adj[n,m]) * (sup[m,o] / D[m]),  D[m] = sum_n exp(adj[n,m])
// p1 is pre-scaled by log2(e) so adj accumulates in log2 domain -> raw v_exp_f32.
#define BB 8
#define NN 2048
#define FF 512
#define LOG2E 1.4426950408889634f

typedef __attribute__((ext_vector_type(8))) short short8;
typedef __attribute__((ext_vector_type(4))) float floatx4;
typedef __attribute__((ext_vector_type(2))) float float2v;
typedef __attribute__((ext_vector_type(2))) __bf16 bf16x2;

__device__ __forceinline__ unsigned short f2bf(float f) {
    union { float f; unsigned u; } v; v.f = f;
    unsigned r = v.u + 0x7FFFu + ((v.u >> 16) & 1u);
    return (unsigned short)(r >> 16);
}

__device__ __forceinline__ float fexp2(float x) {
#if __has_builtin(__builtin_amdgcn_exp2f)
    return __builtin_amdgcn_exp2f(x);
#else
    return __expf(x * 0.69314718056f);
#endif
}

// packed f32x2 -> bf16x2 (v_cvt_pk_bf16_f32 on gfx950), RNE
__device__ __forceinline__ void pk_store(unsigned short* p0, unsigned short* p1,
                                         float a, float b) {
    union { bf16x2 h; unsigned short s[2]; } u;
    float2v v; v.x = a; v.y = b;
    u.h = __builtin_convertvector(v, bf16x2);
    *p0 = u.s[0]; *p1 = u.s[1];
}

// ---------------------------------------------------------------------------
// BT-GEMM, bf16 MFMA: C[i,j] = sum_k A[i*a_ld+k] * B[j*b_ld+k]
// C row i = A row (MFMA i-dim: quad*4+reg), C col j = B row (MFMA j-dim: fl)
// modes: 0 = fp32 out + bias[j]; 1 = bf16 out; 2 = bf16 exp2(out) + Dsum[j] colsum
// 128x128 tile, BK=64 (32 KB LDS), 256 thr = 4 waves (2x2), 4x4 16x16x32 frags.
// LDS chunk XOR swizzle (slot kc^(row&7)): conflict-free (verified r5: 0 conflicts).
// Staging addresses strength-reduced: per-lane offsets loop-invariant, uniform
// base pointer advances by 64 elems/iter.
// ---------------------------------------------------------------------------
__global__ __launch_bounds__(256) void gemm_mfma_bt(
    const unsigned short* __restrict__ A, const unsigned short* __restrict__ B,
    void* __restrict__ Cv, const float* __restrict__ bias, float* __restrict__ Dsum,
    int M, int Nc, int K, int a_ld, int b_ld, int ldc,
    long a_batch, long b_batch, long c_batch, int mode)
{
    __shared__ __align__(16) unsigned short Alds[128 * 64];
    __shared__ __align__(16) unsigned short Blds[128 * 64];

    const int tid  = threadIdx.x;
    const int wave = tid >> 6;
    const int lane = tid & 63;
    const int bz   = blockIdx.z;

    const int m0 = blockIdx.y * 128;   // A-row tile (C rows)
    const int n0 = blockIdx.x * 128;   // B-row tile (C cols)

    const unsigned short* Aptr = A + (long)bz * a_batch + (long)m0 * a_ld;
    const unsigned short* Bptr = B + (long)bz * b_batch + (long)n0 * b_ld;

    const int wm   = (wave >> 1) * 64;
    const int wn   = (wave & 1) * 64;
    const int fl   = lane & 15;
    const int quad = lane >> 4;

    // loop-invariant per-lane staging offsets (elements) and LDS bases
    int offA[4], offB[4], cb[4];
    #pragma unroll
    for (int issue = 0; issue < 4; ++issue) {
        const int cbase = issue * 256 + wave * 64;
        const int c = cbase + lane;
        const int row = c >> 3;
        const int kq = ((c & 7) ^ ((c >> 3) & 7)) * 8;
        offA[issue] = row * a_ld + kq;
        offB[issue] = row * b_ld + kq;
        cb[issue] = cbase * 8;
    }

    floatx4 acc[4][4] = {};

    for (int k0 = 0; k0 < K; k0 += 64) {
        #pragma unroll
        for (int issue = 0; issue < 4; ++issue) {
            __builtin_amdgcn_global_load_lds(
                (const __attribute__((address_space(1))) void*)(Aptr + offA[issue]),
                (__attribute__((address_space(3))) void*)&Alds[cb[issue]], 16, 0, 0);
            __builtin_amdgcn_global_load_lds(
                (const __attribute__((address_space(1))) void*)(Bptr + offB[issue]),
                (__attribute__((address_space(3))) void*)&Blds[cb[issue]], 16, 0, 0);
        }
        Aptr += 64; Bptr += 64;
        __syncthreads();

        #pragma unroll
        for (int s = 0; s < 2; ++s) {
            short8 af[4], bf[4];
            const int slot = ((s * 4 + quad) ^ (fl & 7)) * 8;
            #pragma unroll
            for (int i = 0; i < 4; ++i)
                af[i] = *(const short8*)&Alds[(wm + i * 16 + fl) * 64 + slot];
            #pragma unroll
            for (int j = 0; j < 4; ++j)
                bf[j] = *(const short8*)&Blds[(wn + j * 16 + fl) * 64 + slot];
            #pragma unroll
            for (int i = 0; i < 4; ++i)
                #pragma unroll
                for (int j = 0; j < 4; ++j)
                    acc[i][j] = __builtin_amdgcn_mfma_f32_16x16x32_bf16(af[i], bf[j], acc[i][j], 0, 0, 0);
        }
        __syncthreads();
    }

    // Epilogue: col(j) = fl across lanes -> 32B contiguous per quad per store.
    if (mode == 0) {
        float* Cb = (float*)Cv + (long)bz * c_batch;
        #pragma unroll
        for (int j = 0; j < 4; ++j) {
            const int ng = n0 + wn + j * 16 + fl;
            const float badd = bias ? bias[ng] : 0.0f;
            #pragma unroll
            for (int i = 0; i < 4; ++i) {
                const int mg = m0 + wm + i * 16 + quad * 4;
                #pragma unroll
                for (int r = 0; r < 4; ++r)
                    Cb[(long)(mg + r) * ldc + ng] = acc[i][j][r] + badd;
            }
        }
    } else if (mode == 1) {
        unsigned short* Cb = (unsigned short*)Cv + (long)bz * c_batch;
        #pragma unroll
        for (int j = 0; j < 4; ++j) {
            const int ng = n0 + wn + j * 16 + fl;
            #pragma unroll
            for (int i = 0; i < 4; ++i) {
                const int mg = m0 + wm + i * 16 + quad * 4;
                pk_store(&Cb[(long)(mg + 0) * ldc + ng], &Cb[(long)(mg + 1) * ldc + ng],
                         acc[i][j][0], acc[i][j][1]);
                pk_store(&Cb[(long)(mg + 2) * ldc + ng], &Cb[(long)(mg + 3) * ldc + ng],
                         acc[i][j][2], acc[i][j][3]);
            }
        }
    } else {
        // mode 2: acc is log2-domain; E = 2^acc bf16; Dsum[col] += column sums.
        unsigned short* Cb = (unsigned short*)Cv + (long)bz * c_batch;
        float* Db = Dsum + (long)bz * NN;
        #pragma unroll
        for (int i = 0; i < 4; ++i)
            #pragma unroll
            for (int j = 0; j < 4; ++j)
                #pragma unroll
                for (int r = 0; r < 4; ++r)
                    acc[i][j][r] = fexp2(acc[i][j][r]);
        #pragma unroll
        for (int j = 0; j < 4; ++j) {
            const int ng = n0 + wn + j * 16 + fl;
            float csum = 0.f;
            #pragma unroll
            for (int i = 0; i < 4; ++i) {
                const int mg = m0 + wm + i * 16 + quad * 4;
                csum += acc[i][j][0] + acc[i][j][1] + acc[i][j][2] + acc[i][j][3];
                pk_store(&Cb[(long)(mg + 0) * ldc + ng], &Cb[(long)(mg + 1) * ldc + ng],
                         acc[i][j][0], acc[i][j][1]);
                pk_store(&Cb[(long)(mg + 2) * ldc + ng], &Cb[(long)(mg + 3) * ldc + ng],
                         acc[i][j][2], acc[i][j][3]);
            }
            csum += __shfl_xor(csum, 16);
            csum += __shfl_xor(csum, 32);
            if (quad == 0) atomicAdd(&Db[ng], csum);
        }
    }
}

// fused fp32->bf16 convert for x, w_one (scaled by log2e), w_two
__global__ __launch_bounds__(256) void convert_all(
    const float* __restrict__ x, const float* __restrict__ w1, const float* __restrict__ w2,
    unsigned short* __restrict__ xb, unsigned short* __restrict__ w1b, unsigned short* __restrict__ w2b)
{
    const long NX = (long)BB * NN * FF / 8;
    const long NW = (long)FF * FF / 8;
    long t = (long)blockIdx.x * 256 + threadIdx.x;
    const float* in; unsigned short* out; float sc = 1.0f;
    if (t < NX) { in = x; out = xb; }
    else if (t < NX + NW) { in = w1; out = w1b; t -= NX; sc = LOG2E; }
    else if (t < NX + 2 * NW) { in = w2; out = w2b; t -= NX + NW; }
    else return;
    const long i = t * 8;
    float4 a = *(const float4*)(in + i);
    float4 b = *(const float4*)(in + i + 4);
    union { bf16x2 h[4]; short8 s8; } u;
    float2v v;
    v.x = a.x * sc; v.y = a.y * sc; u.h[0] = __builtin_convertvector(v, bf16x2);
    v.x = a.z * sc; v.y = a.w * sc; u.h[1] = __builtin_convertvector(v, bf16x2);
    v.x = b.x * sc; v.y = b.y * sc; u.h[2] = __builtin_convertvector(v, bf16x2);
    v.x = b.z * sc; v.y = b.w * sc; u.h[3] = __builtin_convertvector(v, bf16x2);
    *(short8*)(out + i) = u.s8;
}

// out[o,f] = bf16(in[f,o]) for dim x dim fp32 (dim % 32 == 0)
__global__ __launch_bounds__(256) void transpose_convert(
    const float* __restrict__ in, unsigned short* __restrict__ out, int dim)
{
    __shared__ float t[32][33];
    const int tx = threadIdx.x & 31, ty = threadIdx.x >> 5;
    const int x0 = blockIdx.x * 32, y0 = blockIdx.y * 32;
    #pragma unroll
    for (int k = 0; k < 32; k += 8)
        t[ty + k][tx] = in[(long)(y0 + ty + k) * dim + x0 + tx];
    __syncthreads();
    #pragma unroll
    for (int k = 0; k < 32; k += 8)
        out[(long)(x0 + ty + k) * dim + y0 + tx] = f2bf(t[tx][ty + k]);
}

__global__ __launch_bounds__(256) void zero_f32(float* __restrict__ p, long n)
{
    long i = (long)blockIdx.x * 256 + threadIdx.x;
    if (i < n) p[i] = 0.0f;
}

// supT[o,m] = bf16( sup[m,o] / D[m] ); sup[m,o] = Call[m*1536 + 1024 + o] (bf16).
__global__ __launch_bounds__(256) void scale_transpose(
    const unsigned short* __restrict__ Call, const float* __restrict__ D,
    unsigned short* __restrict__ supT, int batch0)
{
    __shared__ float t[32][33];
    __shared__ float rD[32];
    const int tx = threadIdx.x & 31, ty = threadIdx.x >> 5;
    const int mt = blockIdx.x * 32, ot = blockIdx.y * 32;
    const int b = batch0 + blockIdx.z;
    const unsigned short* Cb = Call + (long)b * NN * 1536;
    unsigned short* Tb = supT + (long)b * NN * FF;
    if (threadIdx.x < 32) rD[threadIdx.x] = 1.0f / D[(long)b * NN + mt + threadIdx.x];
    __syncthreads();
    #pragma unroll
    for (int k = 0; k < 32; k += 8) {
        unsigned short u = Cb[(long)(mt + ty + k) * 1536 + 1024 + ot + tx];
        union { unsigned uu; float f; } cv; cv.uu = ((unsigned)u) << 16;
        t[ty + k][tx] = cv.f;
    }
    __syncthreads();
    #pragma unroll
    for (int k = 0; k < 32; k += 8)
        Tb[(long)(ot + ty + k) * NN + mt + tx] = f2bf(t[tx][ty + k] * rD[tx]);
}

extern "C" void kernel_launch(void* const* d_in, const int* in_sizes, int n_in,
                              void* d_out, int out_size, void* d_ws, size_t ws_size,
                              hipStream_t stream)
{
    const float* x      = (const float*)d_in[0];
    const float* weight = (const float*)d_in[1];
    const float* bias   = (const float*)d_in[2];
    const float* w_one  = (const float*)d_in[3];
    const float* w_two  = (const float*)d_in[4];
    float* out = (float*)d_out;

    const long NF  = (long)NN * FF;      // 1,048,576
    const long NN2 = (long)NN * NN;      // 4,194,304
    const long CROW = 1536;              // C_all row stride (p1|p2|sup)

    // workspace carve
    char* p = (char*)d_ws;
    unsigned short* xb    = (unsigned short*)p; p += (size_t)BB * NF * 2;          // 16 MB
    unsigned short* Wall  = (unsigned short*)p; p += (size_t)CROW * FF * 2;        // 1.5 MB
    unsigned short* Call  = (unsigned short*)p; p += (size_t)BB * NN * CROW * 2;   // 48 MB
    unsigned short* supT  = (unsigned short*)p; p += (size_t)BB * NF * 2;          // 16 MB
    float*          Dsum  = (float*)p;          p += (size_t)BB * NN * 4;          // 64 KB
    unsigned short* E     = (unsigned short*)p;                                    // 64 MB (full) or 8 MB (batch)
    unsigned short* w1b = Wall;
    unsigned short* w2b = Wall + (size_t)FF * FF;
    unsigned short* wTb = Wall + (size_t)2 * FF * FF;

    const size_t fixed = (size_t)(p - (char*)d_ws);
    const bool full = ws_size >= fixed + (size_t)BB * NN2 * 2;

    dim3 blk(256);

    // 1) converts (w1 pre-scaled by log2e)
    convert_all<<<dim3(4352), blk, 0, stream>>>(x, w_one, w_two, xb, w1b, w2b);
    transpose_convert<<<dim3(FF / 32, FF / 32), blk, 0, stream>>>(weight, wTb, FF);
    zero_f32<<<dim3((BB * NN) / 256), blk, 0, stream>>>(Dsum, BB * NN);

    // 2) Call[n, e] = x[n,:]·Wall[e,:]   (rows n = A = xb, cols e = B = Wall)
    gemm_mfma_bt<<<dim3(CROW / 128, NN / 128, BB), blk, 0, stream>>>(
        xb, Wall, Call, nullptr, nullptr, NN, (int)CROW, FF,
        FF, FF, (int)CROW, NF, 0, NN * CROW, 1);

    if (full) {
        // 3) E[n,m] = exp2(p1·log2e dot p2); Dsum[b,m] += colsums.
        gemm_mfma_bt<<<dim3(NN / 128, NN / 128, BB), blk, 0, stream>>>(
            Call, Call + FF, E, nullptr, Dsum, NN, NN, FF,
            (int)CROW, (int)CROW, NN, NN * CROW, NN * CROW, NN2, 2);
        // 4) supT[o,m] = sup[m,o]/D[m]
        scale_transpose<<<dim3(NN / 32, FF / 32, BB), blk, 0, stream>>>(Call, Dsum, supT, 0);
        // 5) out[n,o] = E[n,:]·supT[o,:] + bias[o]
        gemm_mfma_bt<<<dim3(FF / 128, NN / 128, BB), blk, 0, stream>>>(
            E, supT, out, bias, nullptr, NN, FF, NN,
            NN, NN, FF, NN2, NF, NF, 0);
    } else {
        for (int b = 0; b < BB; ++b) {
            const unsigned short* Cb = Call + (size_t)b * NN * CROW;
            gemm_mfma_bt<<<dim3(NN / 128, NN / 128, 1), blk, 0, stream>>>(
                Cb, Cb + FF, E, nullptr, Dsum + (size_t)b * NN, NN, NN, FF,
                (int)CROW, (int)CROW, NN, 0, 0, 0, 2);
            scale_transpose<<<dim3(NN / 32, FF / 32, 1), blk, 0, stream>>>(Call, Dsum, supT, b);
            gemm_mfma_bt<<<dim3(FF / 128, NN / 128, 1), blk, 0, stream>>>(
                E, supT + (size_t)b * NF, out + (size_t)b * NF, bias, nullptr, NN, FF, NN,
                NN, NN, FF, 0, 0, 0, 0);
        }
    }
}